// Round 10
// baseline (492.690 us; speedup 1.0000x reference)
//
#include <hip/hip_runtime.h>
#include <cstdint>
#include <cstddef>

#define NN 100000
#define NE 1600000
#define BSH 9
#define NBUCK 196          // ceil(NN / 512)
#define CAP 9216           // padded bucket stride (mean 8192, +11 sigma)
#define P3_CHUNK 8192
#define P3_BLOCKS 196      // ceil(NE / P3_CHUNK)

typedef __attribute__((ext_vector_type(8))) short short8;
typedef __attribute__((ext_vector_type(4))) float f32x4;

// ---------------- split-bf16 helpers ----------------
// pack_split(v): bits[15:0] = hi bf16 (RN), bits[31:16] = lo bf16 (RN of residual); v ~= hi + lo

__device__ inline unsigned pack_split(float v) {
    unsigned u = __builtin_bit_cast(unsigned, v);
    unsigned hi = (u + 0x7fffu + ((u >> 16) & 1u)) >> 16;
    float vh = __builtin_bit_cast(float, hi << 16);
    float r = v - vh;
    unsigned u2 = __builtin_bit_cast(unsigned, r);
    unsigned lo = (u2 + 0x7fffu + ((u2 >> 16) & 1u)) >> 16;
    return hi | (lo << 16);
}

__device__ inline unsigned short rnb(float v) {  // RN-even bf16
    unsigned u = __builtin_bit_cast(unsigned, v);
    return (unsigned short)((u + 0x7fffu + ((u >> 16) & 1u)) >> 16);
}

__device__ inline float bf2f(unsigned short u) {
    return __builtin_bit_cast(float, (unsigned)u << 16);
}

// ---------------- CSR build: padded-bucket counting sort ----------------

__global__ __launch_bounds__(256) void k_partition(const int* __restrict__ srce, const int* __restrict__ dste,
                                                   int* __restrict__ gcur, int* __restrict__ tmp) {
    __shared__ int h[NBUCK], lstart[NBUCK], gbase[NBUCK], scn[256];
    __shared__ int s_pack[P3_CHUNK];
    __shared__ int s_gad[P3_CHUNK];
    const int tid = threadIdx.x;
    const int base = blockIdx.x * P3_CHUNK;
    if (tid < NBUCK) h[tid] = 0;
    __syncthreads();
    int rank[P3_CHUNK / 256];
#pragma unroll
    for (int i = 0; i < P3_CHUNK / 256; i++) {
        int idx = base + i * 256 + tid;
        if (idx < NE) rank[i] = atomicAdd(&h[dste[idx] >> BSH], 1);
    }
    __syncthreads();
    int hv = (tid < NBUCK) ? h[tid] : 0;
    if (tid < NBUCK) gbase[tid] = atomicAdd(&gcur[tid], hv);
    scn[tid] = hv;
    __syncthreads();
    for (int off = 1; off < 256; off <<= 1) {
        int u = 0;
        if (tid >= off) u = scn[tid - off];
        __syncthreads();
        scn[tid] += u;
        __syncthreads();
    }
    if (tid < NBUCK) lstart[tid] = scn[tid] - hv;
    __syncthreads();
#pragma unroll
    for (int i = 0; i < P3_CHUNK / 256; i++) {
        int idx = base + i * 256 + tid;
        if (idx < NE) {
            int d = dste[idx], s = srce[idx];
            int b = d >> BSH;
            int slot = lstart[b] + rank[i];
            s_pack[slot] = (s << BSH) | (d & ((1 << BSH) - 1));
            s_gad[slot] = gbase[b] + rank[i];
        }
    }
    __syncthreads();
    int chunkN = NE - base;
    if (chunkN > P3_CHUNK) chunkN = P3_CHUNK;
#pragma unroll
    for (int i = 0; i < P3_CHUNK / 256; i++) {
        int slot = i * 256 + tid;
        if (slot < chunkN) tmp[s_gad[slot]] = s_pack[slot];
    }
}

// per-bucket counting sort (512 local nodes) -> row_ptr, rc (count), inv_deg, col
__global__ __launch_bounds__(256) void k_bucket(const int* __restrict__ tmp, const int* __restrict__ gend,
                                                int* __restrict__ row_ptr, int* __restrict__ rc,
                                                int* __restrict__ col, float* __restrict__ invd) {
    __shared__ int cnt[512], cur[512], scn[256];
    const int b = blockIdx.x, tid = threadIdx.x;
    const int base = b * CAP;
    const int n = gend[b] - base;
    cnt[tid] = 0;
    cnt[tid + 256] = 0;
    __syncthreads();
    for (int k = tid; k < n; k += 256) atomicAdd(&cnt[tmp[base + k] & 511], 1);
    __syncthreads();
    int c0 = cnt[2 * tid], c1 = cnt[2 * tid + 1], s = c0 + c1;
    scn[tid] = s;
    __syncthreads();
    for (int off = 1; off < 256; off <<= 1) {
        int u = 0;
        if (tid >= off) u = scn[tid - off];
        __syncthreads();
        scn[tid] += u;
        __syncthreads();
    }
    int excl = scn[tid] - s;
    int node = (b << BSH) + 2 * tid;
    if (node < NN) {
        row_ptr[node] = base + excl;
        rc[node] = c0;
        invd[node] = c0 ? 1.0f / (float)c0 : 0.0f;
    }
    if (node + 1 < NN) {
        row_ptr[node + 1] = base + excl + c0;
        rc[node + 1] = c1;
        invd[node + 1] = c1 ? 1.0f / (float)c1 : 0.0f;
    }
    cur[2 * tid] = base + excl;
    cur[2 * tid + 1] = base + excl + c0;
    __syncthreads();
    for (int k = tid; k < n; k += 256) {
        int p = tmp[base + k];
        int pos = atomicAdd(&cur[p & 511], 1);
        col[pos] = p >> BSH;
    }
}

// ---------------- fused conversions: x->bf16hi, weight splits, biasPQ, gcur init ----------------
// blocks [0, 6250): Xh;  blocks [6250, 6540): weight planes / biasPQ / gcur

#define XHI_BLOCKS 6250   // NN*64/4/256

__global__ __launch_bounds__(256) void k_conv(const float* __restrict__ x,
                                              const float* __restrict__ Wl0, const float* __restrict__ Wr0,
                                              const float* __restrict__ Wl1, const float* __restrict__ Wr1,
                                              const float* __restrict__ Wl2, const float* __restrict__ Wr2,
                                              const float* __restrict__ Wd1, const float* __restrict__ bl2,
                                              unsigned short* __restrict__ Xh,
                                              unsigned short* __restrict__ Wh, unsigned short* __restrict__ Wl,
                                              float* __restrict__ biasPQ, int* __restrict__ gcur) {
    if (blockIdx.x < XHI_BLOCKS) {
        int i = blockIdx.x * 256 + threadIdx.x;  // x4 elems
        float4 v = ((const float4*)x)[i];
        ushort4 o = {rnb(v.x), rnb(v.y), rnb(v.z), rnb(v.w)};
        ((ushort4*)Xh)[i] = o;
        return;
    }
    int i = (blockIdx.x - XHI_BLOCKS) * 256 + threadIdx.x;
    float v = 0.f;
    bool valid = true;
    if (i < 8192) v = Wl0[i];
    else if (i < 16384) v = Wr0[i - 8192];
    else if (i < 32768) v = Wl1[i - 16384];
    else if (i < 49152) v = Wr1[i - 32768];
    else if (i < 57344) v = Wl2[i - 49152];
    else if (i < 65536) v = Wr2[i - 57344];
    else if (i < 73728) v = Wd1[i - 65536];
    else valid = false;
    if (valid) {
        unsigned ps = pack_split(v);
        Wh[i] = (unsigned short)ps;
        Wl[i] = (unsigned short)(ps >> 16);
    }
    if (i >= 73728 && i < 73856) {
        int j = i - 73728;
        biasPQ[j] = (j < 64) ? 0.f : bl2[j - 64];
    }
    if (i >= 73856 && i < 73856 + NBUCK) {
        int j = i - 73856;
        gcur[j] = j * CAP;
    }
}

// ---------------- aggregation (one wave per node, shfl index broadcast, 8-deep MLP) ----------------

// L0: gather Xh (bf16, [NN][64]) -> Agg0 planes
__global__ __launch_bounds__(256) void k_agg64h(const unsigned short* __restrict__ Xh, const int* __restrict__ row_ptr,
                                                const int* __restrict__ rc, const int* __restrict__ col,
                                                const float* __restrict__ invd,
                                                unsigned short* __restrict__ Ah, unsigned short* __restrict__ Al) {
    int node = blockIdx.x * 4 + (threadIdx.x >> 6);
    int lane = threadIdx.x & 63;
    int start = row_ptr[node], end = start + rc[node];
    float a0 = 0.f, a1 = 0.f, a2 = 0.f, a3 = 0.f, a4 = 0.f, a5 = 0.f, a6 = 0.f, a7 = 0.f;
    for (int cs = start; cs < end; cs += 64) {
        int n = end - cs;
        if (n > 64) n = 64;
        int my = (lane < n) ? col[cs + lane] : 0;
        int j = 0;
        for (; j + 8 <= n; j += 8) {
            int s0 = __shfl(my, j + 0), s1 = __shfl(my, j + 1);
            int s2 = __shfl(my, j + 2), s3 = __shfl(my, j + 3);
            int s4 = __shfl(my, j + 4), s5 = __shfl(my, j + 5);
            int s6 = __shfl(my, j + 6), s7 = __shfl(my, j + 7);
            float v0 = bf2f(Xh[(size_t)s0 * 64 + lane]);
            float v1 = bf2f(Xh[(size_t)s1 * 64 + lane]);
            float v2 = bf2f(Xh[(size_t)s2 * 64 + lane]);
            float v3 = bf2f(Xh[(size_t)s3 * 64 + lane]);
            float v4 = bf2f(Xh[(size_t)s4 * 64 + lane]);
            float v5 = bf2f(Xh[(size_t)s5 * 64 + lane]);
            float v6 = bf2f(Xh[(size_t)s6 * 64 + lane]);
            float v7 = bf2f(Xh[(size_t)s7 * 64 + lane]);
            a0 += v0; a1 += v1; a2 += v2; a3 += v3;
            a4 += v4; a5 += v5; a6 += v6; a7 += v7;
        }
        for (; j < n; j++) {
            int s = __shfl(my, j);
            a0 += bf2f(Xh[(size_t)s * 64 + lane]);
        }
    }
    float acc = ((a0 + a1) + (a2 + a3)) + ((a4 + a5) + (a6 + a7));
    unsigned ps = pack_split(acc * invd[node]);
    __builtin_nontemporal_store((unsigned short)ps, Ah + (size_t)node * 64 + lane);
    __builtin_nontemporal_store((unsigned short)(ps >> 16), Al + (size_t)node * 64 + lane);
}

// L1: gather G0hi (bf16, [NN][128]) -> Agg1 planes.
// XCD column-affinity split: half = blockIdx & 1 selects cols [half*64, half*64+64);
// with round-robin blockIdx->XCD, even XCDs only touch cols 0-63, odd only 64-127,
// so each per-XCD L2 caches a 12.8 MB half-table instead of the full 25.6 MB.
__global__ __launch_bounds__(256) void k_agg128h(const unsigned short* __restrict__ Gh, const int* __restrict__ row_ptr,
                                                 const int* __restrict__ rc, const int* __restrict__ col,
                                                 const float* __restrict__ invd,
                                                 unsigned short* __restrict__ Ah, unsigned short* __restrict__ Al) {
    int half = blockIdx.x & 1;
    int node = (blockIdx.x >> 1) * 4 + (threadIdx.x >> 6);
    int lane = threadIdx.x & 63;
    int cix = half * 64 + lane;
    const unsigned short* G = Gh + cix;
    int start = row_ptr[node], end = start + rc[node];
    float a0 = 0.f, a1 = 0.f, a2 = 0.f, a3 = 0.f, a4 = 0.f, a5 = 0.f, a6 = 0.f, a7 = 0.f;
    for (int cs = start; cs < end; cs += 64) {
        int n = end - cs;
        if (n > 64) n = 64;
        int my = (lane < n) ? col[cs + lane] : 0;
        int j = 0;
        for (; j + 8 <= n; j += 8) {
            int s0 = __shfl(my, j + 0), s1 = __shfl(my, j + 1);
            int s2 = __shfl(my, j + 2), s3 = __shfl(my, j + 3);
            int s4 = __shfl(my, j + 4), s5 = __shfl(my, j + 5);
            int s6 = __shfl(my, j + 6), s7 = __shfl(my, j + 7);
            float v0 = bf2f(G[(size_t)s0 * 128]);
            float v1 = bf2f(G[(size_t)s1 * 128]);
            float v2 = bf2f(G[(size_t)s2 * 128]);
            float v3 = bf2f(G[(size_t)s3 * 128]);
            float v4 = bf2f(G[(size_t)s4 * 128]);
            float v5 = bf2f(G[(size_t)s5 * 128]);
            float v6 = bf2f(G[(size_t)s6 * 128]);
            float v7 = bf2f(G[(size_t)s7 * 128]);
            a0 += v0; a1 += v1; a2 += v2; a3 += v3;
            a4 += v4; a5 += v5; a6 += v6; a7 += v7;
        }
        for (; j < n; j++) {
            int s = __shfl(my, j);
            a0 += bf2f(G[(size_t)s * 128]);
        }
    }
    float acc = ((a0 + a1) + (a2 + a3)) + ((a4 + a5) + (a6 + a7));
    unsigned ps = pack_split(acc * invd[node]);
    __builtin_nontemporal_store((unsigned short)ps, Ah + (size_t)node * 128 + cix);
    __builtin_nontemporal_store((unsigned short)(ps >> 16), Al + (size_t)node * 128 + cix);
}

// L2 tail: h2 = relu(Q + invd * sum Ph[s]) -> h2 planes
__global__ __launch_bounds__(256) void k_aggPh(const unsigned short* __restrict__ Ph, const float* __restrict__ Qf,
                                               const int* __restrict__ row_ptr, const int* __restrict__ rc,
                                               const int* __restrict__ col, const float* __restrict__ invd,
                                               unsigned short* __restrict__ Hh, unsigned short* __restrict__ Hl) {
    int node = blockIdx.x * 4 + (threadIdx.x >> 6);
    int lane = threadIdx.x & 63;
    int start = row_ptr[node], end = start + rc[node];
    float a0 = 0.f, a1 = 0.f, a2 = 0.f, a3 = 0.f, a4 = 0.f, a5 = 0.f, a6 = 0.f, a7 = 0.f;
    for (int cs = start; cs < end; cs += 64) {
        int n = end - cs;
        if (n > 64) n = 64;
        int my = (lane < n) ? col[cs + lane] : 0;
        int j = 0;
        for (; j + 8 <= n; j += 8) {
            int s0 = __shfl(my, j + 0), s1 = __shfl(my, j + 1);
            int s2 = __shfl(my, j + 2), s3 = __shfl(my, j + 3);
            int s4 = __shfl(my, j + 4), s5 = __shfl(my, j + 5);
            int s6 = __shfl(my, j + 6), s7 = __shfl(my, j + 7);
            float v0 = bf2f(Ph[(size_t)s0 * 64 + lane]);
            float v1 = bf2f(Ph[(size_t)s1 * 64 + lane]);
            float v2 = bf2f(Ph[(size_t)s2 * 64 + lane]);
            float v3 = bf2f(Ph[(size_t)s3 * 64 + lane]);
            float v4 = bf2f(Ph[(size_t)s4 * 64 + lane]);
            float v5 = bf2f(Ph[(size_t)s5 * 64 + lane]);
            float v6 = bf2f(Ph[(size_t)s6 * 64 + lane]);
            float v7 = bf2f(Ph[(size_t)s7 * 64 + lane]);
            a0 += v0; a1 += v1; a2 += v2; a3 += v3;
            a4 += v4; a5 += v5; a6 += v6; a7 += v7;
        }
        for (; j < n; j++) {
            int s = __shfl(my, j);
            a0 += bf2f(Ph[(size_t)s * 64 + lane]);
        }
    }
    float acc = ((a0 + a1) + (a2 + a3)) + ((a4 + a5) + (a6 + a7));
    float v = Qf[(size_t)node * 64 + lane] + invd[node] * acc;
    unsigned ps = pack_split(fmaxf(v, 0.f));
    __builtin_nontemporal_store((unsigned short)ps, Hh + (size_t)node * 64 + lane);
    __builtin_nontemporal_store((unsigned short)(ps >> 16), Hl + (size_t)node * 64 + lane);
}

// ---------------- planar split-bf16 MFMA GEMM (BM=64, register-prefetch pipelined) ----------------
// BM=64, BN=128, BK=32; 4 waves (2x2), each wave 32x64 via 2x4 16x16x32 tiles; 3 MFMA per hi/lo pair.

#define LA 40

// load one 32-K tile slice for this thread: r[0..1] = A hi/lo (1 uint4 each), r[2..5] = W hi/lo pairs
template <int K, int AFMT>
__device__ inline void mg_load(const unsigned short* __restrict__ Ah_g, const unsigned short* __restrict__ Al_g,
                               const float* __restrict__ Af_g,
                               const unsigned short* __restrict__ Wh_g, const unsigned short* __restrict__ Wl_g,
                               int gr, int wrow, int ac, int wc, int kt, uint4* r) {
    r[0] = r[1] = (uint4){0, 0, 0, 0};
    if (AFMT == 0) {
        if (gr < NN) {
            r[0] = *(const uint4*)(Ah_g + (size_t)gr * K + kt + ac);
            r[1] = *(const uint4*)(Al_g + (size_t)gr * K + kt + ac);
        }
    } else {
        if (gr < NN) {
            const float4* pf = (const float4*)(Af_g + (size_t)gr * K + kt + ac);
            float4 f0 = pf[0], f1 = pf[1];
            float fs[8] = {f0.x, f0.y, f0.z, f0.w, f1.x, f1.y, f1.z, f1.w};
            alignas(16) unsigned short hh[8], ll[8];
#pragma unroll
            for (int i = 0; i < 8; i++) {
                unsigned ps = pack_split(fs[i]);
                hh[i] = (unsigned short)ps;
                ll[i] = (unsigned short)(ps >> 16);
            }
            r[0] = *(const uint4*)&hh[0];
            r[1] = *(const uint4*)&ll[0];
        }
    }
    const uint4* qh = (const uint4*)(Wh_g + wrow * K + kt + wc);
    r[2] = qh[0]; r[3] = qh[1];
    const uint4* ql = (const uint4*)(Wl_g + wrow * K + kt + wc);
    r[4] = ql[0]; r[5] = ql[1];
}

template <int K, int AFMT>  // AFMT: 0 = planar bf16 planes, 1 = fp32 source (split on the fly)
__device__ inline void mgp(const unsigned short* __restrict__ Ah_g, const unsigned short* __restrict__ Al_g,
                           const float* __restrict__ Af_g,
                           const unsigned short* __restrict__ Wh_g, const unsigned short* __restrict__ Wl_g,
                           int m0, unsigned short* sAh, unsigned short* sAl,
                           unsigned short* sBh, unsigned short* sBl,
                           f32x4 (&acc)[2][4], int tid, int wm, int wn, int l15, int quad) {
    const int arow = tid >> 2, ac = (tid & 3) * 8;   // A: 64 rows x 4 threads x 8 shorts
    const int wrow = tid >> 1, wc = (tid & 1) * 16;  // W: 128 rows x 2 threads x 16 shorts
    const int gr = m0 + arow;
    uint4 cur[6];
    mg_load<K, AFMT>(Ah_g, Al_g, Af_g, Wh_g, Wl_g, gr, wrow, ac, wc, 0, cur);
#pragma unroll 1
    for (int kt = 0; kt < K; kt += 32) {
        __syncthreads();
        *(uint4*)(sAh + arow * LA + ac) = cur[0];
        *(uint4*)(sAl + arow * LA + ac) = cur[1];
        *(uint4*)(sBh + wrow * LA + wc) = cur[2]; *(uint4*)(sBh + wrow * LA + wc + 8) = cur[3];
        *(uint4*)(sBl + wrow * LA + wc) = cur[4]; *(uint4*)(sBl + wrow * LA + wc + 8) = cur[5];
        __syncthreads();
        if (kt + 32 < K)  // prefetch next tile; loads fly during ds_read + MFMA below
            mg_load<K, AFMT>(Ah_g, Al_g, Af_g, Wh_g, Wl_g, gr, wrow, ac, wc, kt + 32, cur);
        short8 ah[2], al[2], bh[4], bl[4];
#pragma unroll
        for (int t = 0; t < 2; t++) {
            ah[t] = *(const short8*)(sAh + (wm + t * 16 + l15) * LA + quad * 8);
            al[t] = *(const short8*)(sAl + (wm + t * 16 + l15) * LA + quad * 8);
        }
#pragma unroll
        for (int t = 0; t < 4; t++) {
            bh[t] = *(const short8*)(sBh + (wn + t * 16 + l15) * LA + quad * 8);
            bl[t] = *(const short8*)(sBl + (wn + t * 16 + l15) * LA + quad * 8);
        }
#pragma unroll
        for (int mt = 0; mt < 2; mt++)
#pragma unroll
            for (int nt = 0; nt < 4; nt++) {
                acc[mt][nt] = __builtin_amdgcn_mfma_f32_16x16x32_bf16(ah[mt], bh[nt], acc[mt][nt], 0, 0, 0);
                acc[mt][nt] = __builtin_amdgcn_mfma_f32_16x16x32_bf16(ah[mt], bl[nt], acc[mt][nt], 0, 0, 0);
                acc[mt][nt] = __builtin_amdgcn_mfma_f32_16x16x32_bf16(al[mt], bh[nt], acc[mt][nt], 0, 0, 0);
            }
    }
}

// OMODE: 0 = fp32 C (pitch 128); 1 = planar bf16 C planes (pitch 128);
//        2 = cols<64 -> Ph bf16 (pitch 64), cols>=64 -> Qf fp32 (pitch 64);
//        3 = fused final decoder: out[row,0:2] = relu(C+bias) @ Wd2^T + bd2
// In-place (C planes == A planes) safe: each block writes only its own rows after all its reads.
template <int K1, int K2, int AF1, int AF2, bool RELU, int OMODE>
__global__ __launch_bounds__(256) void k_mgemm(
    const unsigned short* A1h, const unsigned short* A1l, const float* A1f,
    const unsigned short* A2h, const unsigned short* A2l, const float* A2f,
    const unsigned short* __restrict__ W1h, const unsigned short* __restrict__ W1l,
    const unsigned short* __restrict__ W2h, const unsigned short* __restrict__ W2l,
    const float* __restrict__ bias, float* Cf, unsigned short* Chi, unsigned short* Clo,
    unsigned short* Ph, float* Qf,
    const float* __restrict__ Wd2, const float* __restrict__ bd2, float* outp) {
    __shared__ unsigned short sAh[64 * LA], sAl[64 * LA], sBh[128 * LA], sBl[128 * LA];
    const int tid = threadIdx.x;
    const int m0 = blockIdx.x * 64;
    const int wave = tid >> 6, lane = tid & 63;
    const int wm = (wave & 1) * 32, wn = (wave >> 1) * 64;
    const int l15 = lane & 15, quad = lane >> 4;
    f32x4 acc[2][4];
#pragma unroll
    for (int i = 0; i < 2; i++)
#pragma unroll
        for (int j = 0; j < 4; j++) acc[i][j] = (f32x4){0.f, 0.f, 0.f, 0.f};

    mgp<K1, AF1>(A1h, A1l, A1f, W1h, W1l, m0, sAh, sAl, sBh, sBl, acc, tid, wm, wn, l15, quad);
    if (K2 > 0) mgp<K2, AF2>(A2h, A2l, A2f, W2h, W2l, m0, sAh, sAl, sBh, sBl, acc, tid, wm, wn, l15, quad);

    if (OMODE == 3) {
        // fused 128->2 contraction: per-lane nt-sum, shfl_xor over the 16-lane l15 group,
        // then cross-wave combine in LDS.
        __syncthreads();                    // all waves done reading frag LDS
        float* sOut = (float*)sAh;          // [64][2]
        if (tid < 128) sOut[tid] = 0.f;
        __syncthreads();
        float w0[4], w1[4], bv[4];
#pragma unroll
        for (int nt = 0; nt < 4; nt++) {
            int cg = wn + nt * 16 + l15;
            w0[nt] = Wd2[cg];
            w1[nt] = Wd2[128 + cg];
            bv[nt] = bias[cg];
        }
#pragma unroll
        for (int mt = 0; mt < 2; mt++) {
#pragma unroll
            for (int r = 0; r < 4; r++) {
                float s0 = 0.f, s1 = 0.f;
#pragma unroll
                for (int nt = 0; nt < 4; nt++) {
                    float v = fmaxf(acc[mt][nt][r] + bv[nt], 0.f);
                    s0 += v * w0[nt];
                    s1 += v * w1[nt];
                }
                s0 += __shfl_xor(s0, 1); s1 += __shfl_xor(s1, 1);
                s0 += __shfl_xor(s0, 2); s1 += __shfl_xor(s1, 2);
                s0 += __shfl_xor(s0, 4); s1 += __shfl_xor(s1, 4);
                s0 += __shfl_xor(s0, 8); s1 += __shfl_xor(s1, 8);
                if (l15 == 0) {
                    int lr = wm + mt * 16 + quad * 4 + r;
                    atomicAdd(&sOut[lr * 2 + 0], s0);
                    atomicAdd(&sOut[lr * 2 + 1], s1);
                }
            }
        }
        __syncthreads();
        if (tid < 128) {
            int lr = tid >> 1, c = tid & 1;
            int row = m0 + lr;
            if (row < NN) outp[(size_t)row * 2 + c] = sOut[lr * 2 + c] + bd2[c];
        }
        return;
    }

#pragma unroll
    for (int mt = 0; mt < 2; mt++) {
        int rbase = m0 + wm + mt * 16 + quad * 4;
#pragma unroll
        for (int nt = 0; nt < 4; nt++) {
            int cg = wn + nt * 16 + l15;
            float bv = bias[cg];
#pragma unroll
            for (int r = 0; r < 4; r++) {
                int row = rbase + r;
                if (row < NN) {
                    float v = acc[mt][nt][r] + bv;
                    if (RELU) v = fmaxf(v, 0.f);
                    if (OMODE == 0) {
                        Cf[(size_t)row * 128 + cg] = v;
                    } else if (OMODE == 1) {
                        unsigned ps = pack_split(v);
                        Chi[(size_t)row * 128 + cg] = (unsigned short)ps;
                        Clo[(size_t)row * 128 + cg] = (unsigned short)(ps >> 16);
                    } else {
                        if (cg < 64) Ph[(size_t)row * 64 + cg] = rnb(v);
                        else Qf[(size_t)row * 64 + cg - 64] = v;
                    }
                }
            }
        }
    }
}

// ---------------- launch ----------------

extern "C" void kernel_launch(void* const* d_in, const int* in_sizes, int n_in,
                              void* d_out, int out_size, void* d_ws, size_t ws_size,
                              hipStream_t stream) {
    const float* x   = (const float*)d_in[0];
    const int*   ei  = (const int*)d_in[1];
    const float* Wl0 = (const float*)d_in[2];
    const float* bl0 = (const float*)d_in[3];
    const float* Wr0 = (const float*)d_in[4];
    const float* Wl1 = (const float*)d_in[5];
    const float* bl1 = (const float*)d_in[6];
    const float* Wr1 = (const float*)d_in[7];
    const float* Wl2 = (const float*)d_in[8];
    const float* bl2 = (const float*)d_in[9];
    const float* Wr2 = (const float*)d_in[10];
    const float* Wd1 = (const float*)d_in[11];
    const float* bd1 = (const float*)d_in[12];
    const float* Wd2 = (const float*)d_in[13];
    const float* bd2 = (const float*)d_in[14];
    float* out = (float*)d_out;

    char* ws = (char*)d_ws;
    size_t off = 0;
    auto alloc = [&](size_t bytes) {
        char* p = ws + off;
        off = (off + bytes + 255) & ~(size_t)255;
        return p;
    };
    int*            gcur    = (int*)alloc((size_t)NBUCK * 4);
    int*            row_ptr = (int*)alloc((size_t)NN * 4);
    int*            rc      = (int*)alloc((size_t)NN * 4);
    float*          invd    = (float*)alloc((size_t)NN * 4);
    float*          biasPQ  = (float*)alloc(128 * 4);
    unsigned short* Wh      = (unsigned short*)alloc((size_t)73728 * 2);
    unsigned short* Wl      = (unsigned short*)alloc((size_t)73728 * 2);
    int*            col     = (int*)alloc((size_t)NBUCK * CAP * 4);  // padded
    char*           R1      = alloc((size_t)NN * 128 * 4);  // 51.2 MB
    char*           R2      = alloc((size_t)NN * 128 * 4);  // 51.2 MB
    (void)ws_size;

    // R1 lifetime: [Xh 12.8 | Agg0h 12.8 | Agg0l 12.8] -> Agg1 planes (51.2) -> [Ph 12.8 | Qf 25.6]
    // R2 lifetime: tmp(CSR, 7.2MB) -> [G0h 25.6 | G0l 25.6] -> H1 in-place -> h2 planes (25.6)
    unsigned short* Xh    = (unsigned short*)R1;
    unsigned short* Agg0h = (unsigned short*)(R1 + 12800000);
    unsigned short* Agg0l = (unsigned short*)(R1 + 25600000);
    unsigned short* Agg1h = (unsigned short*)R1;
    unsigned short* Agg1l = (unsigned short*)(R1 + 25600000);
    unsigned short* Ph    = (unsigned short*)R1;
    float*          Qf    = (float*)(R1 + 12800000);
    int*            tmp   = (int*)R2;  // dead before G0's first write (L0 GEMM)
    unsigned short* G0h   = (unsigned short*)R2;
    unsigned short* G0l   = (unsigned short*)(R2 + 25600000);
    unsigned short* H1h   = G0h;
    unsigned short* H1l   = G0l;
    unsigned short* h2h   = (unsigned short*)R2;
    unsigned short* h2l   = (unsigned short*)(R2 + 12800000);

    const unsigned short* WL0h = Wh,         * WL0l = Wl;
    const unsigned short* WR0h = Wh + 8192,  * WR0l = Wl + 8192;
    const unsigned short* WL1h = Wh + 16384, * WL1l = Wl + 16384;
    const unsigned short* WR1h = Wh + 32768, * WR1l = Wl + 32768;
    const unsigned short* WPQh = Wh + 49152, * WPQl = Wl + 49152;
    const unsigned short* WD1h = Wh + 65536, * WD1l = Wl + 65536;

    const int* srce = ei;
    const int* dste = ei + NE;

    // fused conversions + gcur init (independent of CSR; must precede k_partition for gcur)
    k_conv<<<XHI_BLOCKS + 290, 256, 0, stream>>>(x, Wl0, Wr0, Wl1, Wr1, Wl2, Wr2, Wd1, bl2,
                                                 Xh, Wh, Wl, biasPQ, gcur);

    // CSR build (padded buckets: bases compile-time)
    k_partition<<<P3_BLOCKS, 256, 0, stream>>>(srce, dste, gcur, tmp);
    k_bucket<<<NBUCK, 256, 0, stream>>>(tmp, gcur, row_ptr, rc, col, invd);

    const int gGemm = (NN + 63) / 64;  // 1563
    const int gNode = NN / 4;          // 25000

    // Layer 0: 64 -> 128, ReLU.  A1 = Agg0 planes, A2 = x fp32 (on-the-fly split)
    k_agg64h<<<gNode, 256, 0, stream>>>(Xh, row_ptr, rc, col, invd, Agg0h, Agg0l);
    k_mgemm<64, 64, 0, 1, true, 1><<<gGemm, 256, 0, stream>>>(
        Agg0h, Agg0l, nullptr, nullptr, nullptr, x,
        WL0h, WL0l, WR0h, WR0l, bl0, nullptr, G0h, G0l, nullptr, nullptr,
        nullptr, nullptr, nullptr);

    // Layer 1: 128 -> 128, ReLU (in-place over G0 planes); gather column-split for XCD affinity
    k_agg128h<<<gNode * 2, 256, 0, stream>>>(G0h, row_ptr, rc, col, invd, Agg1h, Agg1l);
    k_mgemm<128, 128, 0, 0, true, 1><<<gGemm, 256, 0, stream>>>(
        Agg1h, Agg1l, nullptr, G0h, G0l, nullptr,
        WL1h, WL1l, WR1h, WR1l, bl1, nullptr, H1h, H1l, nullptr, nullptr,
        nullptr, nullptr, nullptr);

    // Layer 2 (transform-before-aggregate): [P|Q] = h1 @ [Wl2;Wr2]^T + [0;bl2]
    k_mgemm<128, 0, 0, 0, false, 2><<<gGemm, 256, 0, stream>>>(
        H1h, H1l, nullptr, nullptr, nullptr, nullptr,
        WPQh, WPQl, nullptr, nullptr, biasPQ, nullptr, nullptr, nullptr, Ph, Qf,
        nullptr, nullptr, nullptr);
    k_aggPh<<<gNode, 256, 0, stream>>>(Ph, Qf, row_ptr, rc, col, invd, h2h, h2l);

    // Decoder: 64 -> 128 (ReLU) -> 2, final layer fused into the GEMM epilogue
    k_mgemm<64, 0, 0, 0, true, 3><<<gGemm, 256, 0, stream>>>(
        h2h, h2l, nullptr, nullptr, nullptr, nullptr,
        WD1h, WD1l, nullptr, nullptr, bd1, nullptr, nullptr, nullptr, nullptr, nullptr,
        Wd2, bd2, out);
}

// Round 11
// 453.808 us; speedup vs baseline: 1.0857x; 1.0857x over previous
//
#include <hip/hip_runtime.h>
#include <cstdint>
#include <cstddef>

#define NN 100000
#define NE 1600000
#define BSH 9
#define NBUCK 196          // ceil(NN / 512)
#define CAP 9216           // padded bucket stride (mean 8192, +11 sigma)
#define P3_CHUNK 8192
#define P3_BLOCKS 196      // ceil(NE / P3_CHUNK)

typedef __attribute__((ext_vector_type(8))) short short8;
typedef __attribute__((ext_vector_type(4))) float f32x4;

// ---------------- split-bf16 helpers ----------------
// pack_split(v): bits[15:0] = hi bf16 (RN), bits[31:16] = lo bf16 (RN of residual); v ~= hi + lo

__device__ inline unsigned pack_split(float v) {
    unsigned u = __builtin_bit_cast(unsigned, v);
    unsigned hi = (u + 0x7fffu + ((u >> 16) & 1u)) >> 16;
    float vh = __builtin_bit_cast(float, hi << 16);
    float r = v - vh;
    unsigned u2 = __builtin_bit_cast(unsigned, r);
    unsigned lo = (u2 + 0x7fffu + ((u2 >> 16) & 1u)) >> 16;
    return hi | (lo << 16);
}

__device__ inline unsigned short rnb(float v) {  // RN-even bf16
    unsigned u = __builtin_bit_cast(unsigned, v);
    return (unsigned short)((u + 0x7fffu + ((u >> 16) & 1u)) >> 16);
}

__device__ inline float bf2f(unsigned short u) {
    return __builtin_bit_cast(float, (unsigned)u << 16);
}

// ---------------- CSR build: padded-bucket counting sort ----------------

__global__ __launch_bounds__(256) void k_partition(const int* __restrict__ srce, const int* __restrict__ dste,
                                                   int* __restrict__ gcur, int* __restrict__ tmp) {
    __shared__ int h[NBUCK], lstart[NBUCK], gbase[NBUCK], scn[256];
    __shared__ int s_pack[P3_CHUNK];
    __shared__ int s_gad[P3_CHUNK];
    const int tid = threadIdx.x;
    const int base = blockIdx.x * P3_CHUNK;
    if (tid < NBUCK) h[tid] = 0;
    __syncthreads();
    int rank[P3_CHUNK / 256];
#pragma unroll
    for (int i = 0; i < P3_CHUNK / 256; i++) {
        int idx = base + i * 256 + tid;
        if (idx < NE) rank[i] = atomicAdd(&h[dste[idx] >> BSH], 1);
    }
    __syncthreads();
    int hv = (tid < NBUCK) ? h[tid] : 0;
    if (tid < NBUCK) gbase[tid] = atomicAdd(&gcur[tid], hv);
    scn[tid] = hv;
    __syncthreads();
    for (int off = 1; off < 256; off <<= 1) {
        int u = 0;
        if (tid >= off) u = scn[tid - off];
        __syncthreads();
        scn[tid] += u;
        __syncthreads();
    }
    if (tid < NBUCK) lstart[tid] = scn[tid] - hv;
    __syncthreads();
#pragma unroll
    for (int i = 0; i < P3_CHUNK / 256; i++) {
        int idx = base + i * 256 + tid;
        if (idx < NE) {
            int d = dste[idx], s = srce[idx];
            int b = d >> BSH;
            int slot = lstart[b] + rank[i];
            s_pack[slot] = (s << BSH) | (d & ((1 << BSH) - 1));
            s_gad[slot] = gbase[b] + rank[i];
        }
    }
    __syncthreads();
    int chunkN = NE - base;
    if (chunkN > P3_CHUNK) chunkN = P3_CHUNK;
#pragma unroll
    for (int i = 0; i < P3_CHUNK / 256; i++) {
        int slot = i * 256 + tid;
        if (slot < chunkN) tmp[s_gad[slot]] = s_pack[slot];
    }
}

// per-bucket counting sort (512 local nodes) -> row_ptr, rc (count), inv_deg, col
__global__ __launch_bounds__(256) void k_bucket(const int* __restrict__ tmp, const int* __restrict__ gend,
                                                int* __restrict__ row_ptr, int* __restrict__ rc,
                                                int* __restrict__ col, float* __restrict__ invd) {
    __shared__ int cnt[512], cur[512], scn[256];
    const int b = blockIdx.x, tid = threadIdx.x;
    const int base = b * CAP;
    const int n = gend[b] - base;
    cnt[tid] = 0;
    cnt[tid + 256] = 0;
    __syncthreads();
    for (int k = tid; k < n; k += 256) atomicAdd(&cnt[tmp[base + k] & 511], 1);
    __syncthreads();
    int c0 = cnt[2 * tid], c1 = cnt[2 * tid + 1], s = c0 + c1;
    scn[tid] = s;
    __syncthreads();
    for (int off = 1; off < 256; off <<= 1) {
        int u = 0;
        if (tid >= off) u = scn[tid - off];
        __syncthreads();
        scn[tid] += u;
        __syncthreads();
    }
    int excl = scn[tid] - s;
    int node = (b << BSH) + 2 * tid;
    if (node < NN) {
        row_ptr[node] = base + excl;
        rc[node] = c0;
        invd[node] = c0 ? 1.0f / (float)c0 : 0.0f;
    }
    if (node + 1 < NN) {
        row_ptr[node + 1] = base + excl + c0;
        rc[node + 1] = c1;
        invd[node + 1] = c1 ? 1.0f / (float)c1 : 0.0f;
    }
    cur[2 * tid] = base + excl;
    cur[2 * tid + 1] = base + excl + c0;
    __syncthreads();
    for (int k = tid; k < n; k += 256) {
        int p = tmp[base + k];
        int pos = atomicAdd(&cur[p & 511], 1);
        col[pos] = p >> BSH;
    }
}

// ---------------- fused conversions: x->bf16hi, weight splits, biasPQ, gcur init ----------------
// blocks [0, 6250): Xh;  blocks [6250, 6540): weight planes / biasPQ / gcur

#define XHI_BLOCKS 6250   // NN*64/4/256

__global__ __launch_bounds__(256) void k_conv(const float* __restrict__ x,
                                              const float* __restrict__ Wl0, const float* __restrict__ Wr0,
                                              const float* __restrict__ Wl1, const float* __restrict__ Wr1,
                                              const float* __restrict__ Wl2, const float* __restrict__ Wr2,
                                              const float* __restrict__ Wd1, const float* __restrict__ bl2,
                                              unsigned short* __restrict__ Xh,
                                              unsigned short* __restrict__ Wh, unsigned short* __restrict__ Wl,
                                              float* __restrict__ biasPQ, int* __restrict__ gcur) {
    if (blockIdx.x < XHI_BLOCKS) {
        int i = blockIdx.x * 256 + threadIdx.x;  // x4 elems
        float4 v = ((const float4*)x)[i];
        ushort4 o = {rnb(v.x), rnb(v.y), rnb(v.z), rnb(v.w)};
        ((ushort4*)Xh)[i] = o;
        return;
    }
    int i = (blockIdx.x - XHI_BLOCKS) * 256 + threadIdx.x;
    float v = 0.f;
    bool valid = true;
    if (i < 8192) v = Wl0[i];
    else if (i < 16384) v = Wr0[i - 8192];
    else if (i < 32768) v = Wl1[i - 16384];
    else if (i < 49152) v = Wr1[i - 32768];
    else if (i < 57344) v = Wl2[i - 49152];
    else if (i < 65536) v = Wr2[i - 57344];
    else if (i < 73728) v = Wd1[i - 65536];
    else valid = false;
    if (valid) {
        unsigned ps = pack_split(v);
        Wh[i] = (unsigned short)ps;
        Wl[i] = (unsigned short)(ps >> 16);
    }
    if (i >= 73728 && i < 73856) {
        int j = i - 73728;
        biasPQ[j] = (j < 64) ? 0.f : bl2[j - 64];
    }
    if (i >= 73856 && i < 73856 + NBUCK) {
        int j = i - 73856;
        gcur[j] = j * CAP;
    }
}

// ---------------- aggregation (one wave per node, shfl index broadcast, 8-deep MLP) ----------------

// L0: gather Xh (bf16, [NN][64]) -> Agg0 planes
__global__ __launch_bounds__(256) void k_agg64h(const unsigned short* __restrict__ Xh, const int* __restrict__ row_ptr,
                                                const int* __restrict__ rc, const int* __restrict__ col,
                                                const float* __restrict__ invd,
                                                unsigned short* __restrict__ Ah, unsigned short* __restrict__ Al) {
    int node = blockIdx.x * 4 + (threadIdx.x >> 6);
    int lane = threadIdx.x & 63;
    int start = row_ptr[node], end = start + rc[node];
    float a0 = 0.f, a1 = 0.f, a2 = 0.f, a3 = 0.f, a4 = 0.f, a5 = 0.f, a6 = 0.f, a7 = 0.f;
    for (int cs = start; cs < end; cs += 64) {
        int n = end - cs;
        if (n > 64) n = 64;
        int my = (lane < n) ? col[cs + lane] : 0;
        int j = 0;
        for (; j + 8 <= n; j += 8) {
            int s0 = __shfl(my, j + 0), s1 = __shfl(my, j + 1);
            int s2 = __shfl(my, j + 2), s3 = __shfl(my, j + 3);
            int s4 = __shfl(my, j + 4), s5 = __shfl(my, j + 5);
            int s6 = __shfl(my, j + 6), s7 = __shfl(my, j + 7);
            float v0 = bf2f(Xh[(size_t)s0 * 64 + lane]);
            float v1 = bf2f(Xh[(size_t)s1 * 64 + lane]);
            float v2 = bf2f(Xh[(size_t)s2 * 64 + lane]);
            float v3 = bf2f(Xh[(size_t)s3 * 64 + lane]);
            float v4 = bf2f(Xh[(size_t)s4 * 64 + lane]);
            float v5 = bf2f(Xh[(size_t)s5 * 64 + lane]);
            float v6 = bf2f(Xh[(size_t)s6 * 64 + lane]);
            float v7 = bf2f(Xh[(size_t)s7 * 64 + lane]);
            a0 += v0; a1 += v1; a2 += v2; a3 += v3;
            a4 += v4; a5 += v5; a6 += v6; a7 += v7;
        }
        for (; j < n; j++) {
            int s = __shfl(my, j);
            a0 += bf2f(Xh[(size_t)s * 64 + lane]);
        }
    }
    float acc = ((a0 + a1) + (a2 + a3)) + ((a4 + a5) + (a6 + a7));
    unsigned ps = pack_split(acc * invd[node]);
    __builtin_nontemporal_store((unsigned short)ps, Ah + (size_t)node * 64 + lane);
    __builtin_nontemporal_store((unsigned short)(ps >> 16), Al + (size_t)node * 64 + lane);
}

// L1: gather G0hi (bf16, [NN][128], lane covers cols 2*lane, 2*lane+1) -> Agg1 planes
__global__ __launch_bounds__(256) void k_agg128h(const unsigned short* __restrict__ Gh, const int* __restrict__ row_ptr,
                                                 const int* __restrict__ rc, const int* __restrict__ col,
                                                 const float* __restrict__ invd,
                                                 unsigned short* __restrict__ Ah, unsigned short* __restrict__ Al) {
    int node = blockIdx.x * 4 + (threadIdx.x >> 6);
    int lane = threadIdx.x & 63;
    int start = row_ptr[node], end = start + rc[node];
    float ax0 = 0.f, ax1 = 0.f, ax2 = 0.f, ax3 = 0.f, ax4 = 0.f, ax5 = 0.f, ax6 = 0.f, ax7 = 0.f;
    float ay0 = 0.f, ay1 = 0.f, ay2 = 0.f, ay3 = 0.f, ay4 = 0.f, ay5 = 0.f, ay6 = 0.f, ay7 = 0.f;
    for (int cs = start; cs < end; cs += 64) {
        int n = end - cs;
        if (n > 64) n = 64;
        int my = (lane < n) ? col[cs + lane] : 0;
        int j = 0;
        for (; j + 8 <= n; j += 8) {
            int s0 = __shfl(my, j + 0), s1 = __shfl(my, j + 1);
            int s2 = __shfl(my, j + 2), s3 = __shfl(my, j + 3);
            int s4 = __shfl(my, j + 4), s5 = __shfl(my, j + 5);
            int s6 = __shfl(my, j + 6), s7 = __shfl(my, j + 7);
            unsigned u0 = *(const unsigned*)(Gh + (size_t)s0 * 128 + 2 * lane);
            unsigned u1 = *(const unsigned*)(Gh + (size_t)s1 * 128 + 2 * lane);
            unsigned u2 = *(const unsigned*)(Gh + (size_t)s2 * 128 + 2 * lane);
            unsigned u3 = *(const unsigned*)(Gh + (size_t)s3 * 128 + 2 * lane);
            unsigned u4 = *(const unsigned*)(Gh + (size_t)s4 * 128 + 2 * lane);
            unsigned u5 = *(const unsigned*)(Gh + (size_t)s5 * 128 + 2 * lane);
            unsigned u6 = *(const unsigned*)(Gh + (size_t)s6 * 128 + 2 * lane);
            unsigned u7 = *(const unsigned*)(Gh + (size_t)s7 * 128 + 2 * lane);
            ax0 += bf2f((unsigned short)u0); ay0 += bf2f((unsigned short)(u0 >> 16));
            ax1 += bf2f((unsigned short)u1); ay1 += bf2f((unsigned short)(u1 >> 16));
            ax2 += bf2f((unsigned short)u2); ay2 += bf2f((unsigned short)(u2 >> 16));
            ax3 += bf2f((unsigned short)u3); ay3 += bf2f((unsigned short)(u3 >> 16));
            ax4 += bf2f((unsigned short)u4); ay4 += bf2f((unsigned short)(u4 >> 16));
            ax5 += bf2f((unsigned short)u5); ay5 += bf2f((unsigned short)(u5 >> 16));
            ax6 += bf2f((unsigned short)u6); ay6 += bf2f((unsigned short)(u6 >> 16));
            ax7 += bf2f((unsigned short)u7); ay7 += bf2f((unsigned short)(u7 >> 16));
        }
        for (; j < n; j++) {
            int s = __shfl(my, j);
            unsigned u = *(const unsigned*)(Gh + (size_t)s * 128 + 2 * lane);
            ax0 += bf2f((unsigned short)u);
            ay0 += bf2f((unsigned short)(u >> 16));
        }
    }
    float w = invd[node];
    float sx = (((ax0 + ax1) + (ax2 + ax3)) + ((ax4 + ax5) + (ax6 + ax7))) * w;
    float sy = (((ay0 + ay1) + (ay2 + ay3)) + ((ay4 + ay5) + (ay6 + ay7))) * w;
    unsigned px = pack_split(sx), py = pack_split(sy);
    __builtin_nontemporal_store((px & 0xffffu) | (py << 16), (unsigned*)(Ah + (size_t)node * 128 + 2 * lane));
    __builtin_nontemporal_store((px >> 16) | (py & 0xffff0000u), (unsigned*)(Al + (size_t)node * 128 + 2 * lane));
}

// L2 tail: h2 = relu(Q + invd * sum Ph[s]) -> h2 planes
__global__ __launch_bounds__(256) void k_aggPh(const unsigned short* __restrict__ Ph, const float* __restrict__ Qf,
                                               const int* __restrict__ row_ptr, const int* __restrict__ rc,
                                               const int* __restrict__ col, const float* __restrict__ invd,
                                               unsigned short* __restrict__ Hh, unsigned short* __restrict__ Hl) {
    int node = blockIdx.x * 4 + (threadIdx.x >> 6);
    int lane = threadIdx.x & 63;
    int start = row_ptr[node], end = start + rc[node];
    float a0 = 0.f, a1 = 0.f, a2 = 0.f, a3 = 0.f, a4 = 0.f, a5 = 0.f, a6 = 0.f, a7 = 0.f;
    for (int cs = start; cs < end; cs += 64) {
        int n = end - cs;
        if (n > 64) n = 64;
        int my = (lane < n) ? col[cs + lane] : 0;
        int j = 0;
        for (; j + 8 <= n; j += 8) {
            int s0 = __shfl(my, j + 0), s1 = __shfl(my, j + 1);
            int s2 = __shfl(my, j + 2), s3 = __shfl(my, j + 3);
            int s4 = __shfl(my, j + 4), s5 = __shfl(my, j + 5);
            int s6 = __shfl(my, j + 6), s7 = __shfl(my, j + 7);
            float v0 = bf2f(Ph[(size_t)s0 * 64 + lane]);
            float v1 = bf2f(Ph[(size_t)s1 * 64 + lane]);
            float v2 = bf2f(Ph[(size_t)s2 * 64 + lane]);
            float v3 = bf2f(Ph[(size_t)s3 * 64 + lane]);
            float v4 = bf2f(Ph[(size_t)s4 * 64 + lane]);
            float v5 = bf2f(Ph[(size_t)s5 * 64 + lane]);
            float v6 = bf2f(Ph[(size_t)s6 * 64 + lane]);
            float v7 = bf2f(Ph[(size_t)s7 * 64 + lane]);
            a0 += v0; a1 += v1; a2 += v2; a3 += v3;
            a4 += v4; a5 += v5; a6 += v6; a7 += v7;
        }
        for (; j < n; j++) {
            int s = __shfl(my, j);
            a0 += bf2f(Ph[(size_t)s * 64 + lane]);
        }
    }
    float acc = ((a0 + a1) + (a2 + a3)) + ((a4 + a5) + (a6 + a7));
    float v = Qf[(size_t)node * 64 + lane] + invd[node] * acc;
    unsigned ps = pack_split(fmaxf(v, 0.f));
    __builtin_nontemporal_store((unsigned short)ps, Hh + (size_t)node * 64 + lane);
    __builtin_nontemporal_store((unsigned short)(ps >> 16), Hl + (size_t)node * 64 + lane);
}

// ---------------- planar split-bf16 MFMA GEMM (BM=64, register-prefetch pipelined) ----------------
// BM=64, BN=128, BK=32; 4 waves (2x2), each wave 32x64 via 2x4 16x16x32 tiles; 3 MFMA per hi/lo pair.

#define LA 40

// load one 32-K tile slice for this thread: r[0..1] = A hi/lo (1 uint4 each), r[2..5] = W hi/lo pairs
template <int K, int AFMT>
__device__ inline void mg_load(const unsigned short* __restrict__ Ah_g, const unsigned short* __restrict__ Al_g,
                               const float* __restrict__ Af_g,
                               const unsigned short* __restrict__ Wh_g, const unsigned short* __restrict__ Wl_g,
                               int gr, int wrow, int ac, int wc, int kt, uint4* r) {
    r[0] = r[1] = (uint4){0, 0, 0, 0};
    if (AFMT == 0) {
        if (gr < NN) {
            r[0] = *(const uint4*)(Ah_g + (size_t)gr * K + kt + ac);
            r[1] = *(const uint4*)(Al_g + (size_t)gr * K + kt + ac);
        }
    } else {
        if (gr < NN) {
            const float4* pf = (const float4*)(Af_g + (size_t)gr * K + kt + ac);
            float4 f0 = pf[0], f1 = pf[1];
            float fs[8] = {f0.x, f0.y, f0.z, f0.w, f1.x, f1.y, f1.z, f1.w};
            alignas(16) unsigned short hh[8], ll[8];
#pragma unroll
            for (int i = 0; i < 8; i++) {
                unsigned ps = pack_split(fs[i]);
                hh[i] = (unsigned short)ps;
                ll[i] = (unsigned short)(ps >> 16);
            }
            r[0] = *(const uint4*)&hh[0];
            r[1] = *(const uint4*)&ll[0];
        }
    }
    const uint4* qh = (const uint4*)(Wh_g + wrow * K + kt + wc);
    r[2] = qh[0]; r[3] = qh[1];
    const uint4* ql = (const uint4*)(Wl_g + wrow * K + kt + wc);
    r[4] = ql[0]; r[5] = ql[1];
}

template <int K, int AFMT>  // AFMT: 0 = planar bf16 planes, 1 = fp32 source (split on the fly)
__device__ inline void mgp(const unsigned short* __restrict__ Ah_g, const unsigned short* __restrict__ Al_g,
                           const float* __restrict__ Af_g,
                           const unsigned short* __restrict__ Wh_g, const unsigned short* __restrict__ Wl_g,
                           int m0, unsigned short* sAh, unsigned short* sAl,
                           unsigned short* sBh, unsigned short* sBl,
                           f32x4 (&acc)[2][4], int tid, int wm, int wn, int l15, int quad) {
    const int arow = tid >> 2, ac = (tid & 3) * 8;   // A: 64 rows x 4 threads x 8 shorts
    const int wrow = tid >> 1, wc = (tid & 1) * 16;  // W: 128 rows x 2 threads x 16 shorts
    const int gr = m0 + arow;
    uint4 cur[6];
    mg_load<K, AFMT>(Ah_g, Al_g, Af_g, Wh_g, Wl_g, gr, wrow, ac, wc, 0, cur);
#pragma unroll 1
    for (int kt = 0; kt < K; kt += 32) {
        __syncthreads();
        *(uint4*)(sAh + arow * LA + ac) = cur[0];
        *(uint4*)(sAl + arow * LA + ac) = cur[1];
        *(uint4*)(sBh + wrow * LA + wc) = cur[2]; *(uint4*)(sBh + wrow * LA + wc + 8) = cur[3];
        *(uint4*)(sBl + wrow * LA + wc) = cur[4]; *(uint4*)(sBl + wrow * LA + wc + 8) = cur[5];
        __syncthreads();
        if (kt + 32 < K)  // prefetch next tile; loads fly during ds_read + MFMA below
            mg_load<K, AFMT>(Ah_g, Al_g, Af_g, Wh_g, Wl_g, gr, wrow, ac, wc, kt + 32, cur);
        short8 ah[2], al[2], bh[4], bl[4];
#pragma unroll
        for (int t = 0; t < 2; t++) {
            ah[t] = *(const short8*)(sAh + (wm + t * 16 + l15) * LA + quad * 8);
            al[t] = *(const short8*)(sAl + (wm + t * 16 + l15) * LA + quad * 8);
        }
#pragma unroll
        for (int t = 0; t < 4; t++) {
            bh[t] = *(const short8*)(sBh + (wn + t * 16 + l15) * LA + quad * 8);
            bl[t] = *(const short8*)(sBl + (wn + t * 16 + l15) * LA + quad * 8);
        }
#pragma unroll
        for (int mt = 0; mt < 2; mt++)
#pragma unroll
            for (int nt = 0; nt < 4; nt++) {
                acc[mt][nt] = __builtin_amdgcn_mfma_f32_16x16x32_bf16(ah[mt], bh[nt], acc[mt][nt], 0, 0, 0);
                acc[mt][nt] = __builtin_amdgcn_mfma_f32_16x16x32_bf16(ah[mt], bl[nt], acc[mt][nt], 0, 0, 0);
                acc[mt][nt] = __builtin_amdgcn_mfma_f32_16x16x32_bf16(al[mt], bh[nt], acc[mt][nt], 0, 0, 0);
            }
    }
}

// OMODE: 0 = fp32 C (pitch 128); 1 = planar bf16 C planes (pitch 128);
//        2 = cols<64 -> Ph bf16 (pitch 64), cols>=64 -> Qf fp32 (pitch 64);
//        3 = fused final decoder: out[row,0:2] = relu(C+bias) @ Wd2^T + bd2
// In-place (C planes == A planes) safe: each block writes only its own rows after all its reads.
template <int K1, int K2, int AF1, int AF2, bool RELU, int OMODE>
__global__ __launch_bounds__(256) void k_mgemm(
    const unsigned short* A1h, const unsigned short* A1l, const float* A1f,
    const unsigned short* A2h, const unsigned short* A2l, const float* A2f,
    const unsigned short* __restrict__ W1h, const unsigned short* __restrict__ W1l,
    const unsigned short* __restrict__ W2h, const unsigned short* __restrict__ W2l,
    const float* __restrict__ bias, float* Cf, unsigned short* Chi, unsigned short* Clo,
    unsigned short* Ph, float* Qf,
    const float* __restrict__ Wd2, const float* __restrict__ bd2, float* outp) {
    __shared__ unsigned short sAh[64 * LA], sAl[64 * LA], sBh[128 * LA], sBl[128 * LA];
    const int tid = threadIdx.x;
    const int m0 = blockIdx.x * 64;
    const int wave = tid >> 6, lane = tid & 63;
    const int wm = (wave & 1) * 32, wn = (wave >> 1) * 64;
    const int l15 = lane & 15, quad = lane >> 4;
    f32x4 acc[2][4];
#pragma unroll
    for (int i = 0; i < 2; i++)
#pragma unroll
        for (int j = 0; j < 4; j++) acc[i][j] = (f32x4){0.f, 0.f, 0.f, 0.f};

    mgp<K1, AF1>(A1h, A1l, A1f, W1h, W1l, m0, sAh, sAl, sBh, sBl, acc, tid, wm, wn, l15, quad);
    if (K2 > 0) mgp<K2, AF2>(A2h, A2l, A2f, W2h, W2l, m0, sAh, sAl, sBh, sBl, acc, tid, wm, wn, l15, quad);

    if (OMODE == 3) {
        // fused 128->2 contraction: per-lane nt-sum, shfl_xor over the 16-lane l15 group,
        // then cross-wave combine in LDS.
        __syncthreads();                    // all waves done reading frag LDS
        float* sOut = (float*)sAh;          // [64][2]
        if (tid < 128) sOut[tid] = 0.f;
        __syncthreads();
        float w0[4], w1[4], bv[4];
#pragma unroll
        for (int nt = 0; nt < 4; nt++) {
            int cg = wn + nt * 16 + l15;
            w0[nt] = Wd2[cg];
            w1[nt] = Wd2[128 + cg];
            bv[nt] = bias[cg];
        }
#pragma unroll
        for (int mt = 0; mt < 2; mt++) {
#pragma unroll
            for (int r = 0; r < 4; r++) {
                float s0 = 0.f, s1 = 0.f;
#pragma unroll
                for (int nt = 0; nt < 4; nt++) {
                    float v = fmaxf(acc[mt][nt][r] + bv[nt], 0.f);
                    s0 += v * w0[nt];
                    s1 += v * w1[nt];
                }
                s0 += __shfl_xor(s0, 1); s1 += __shfl_xor(s1, 1);
                s0 += __shfl_xor(s0, 2); s1 += __shfl_xor(s1, 2);
                s0 += __shfl_xor(s0, 4); s1 += __shfl_xor(s1, 4);
                s0 += __shfl_xor(s0, 8); s1 += __shfl_xor(s1, 8);
                if (l15 == 0) {
                    int lr = wm + mt * 16 + quad * 4 + r;
                    atomicAdd(&sOut[lr * 2 + 0], s0);
                    atomicAdd(&sOut[lr * 2 + 1], s1);
                }
            }
        }
        __syncthreads();
        if (tid < 128) {
            int lr = tid >> 1, c = tid & 1;
            int row = m0 + lr;
            if (row < NN) outp[(size_t)row * 2 + c] = sOut[lr * 2 + c] + bd2[c];
        }
        return;
    }

#pragma unroll
    for (int mt = 0; mt < 2; mt++) {
        int rbase = m0 + wm + mt * 16 + quad * 4;
#pragma unroll
        for (int nt = 0; nt < 4; nt++) {
            int cg = wn + nt * 16 + l15;
            float bv = bias[cg];
#pragma unroll
            for (int r = 0; r < 4; r++) {
                int row = rbase + r;
                if (row < NN) {
                    float v = acc[mt][nt][r] + bv;
                    if (RELU) v = fmaxf(v, 0.f);
                    if (OMODE == 0) {
                        Cf[(size_t)row * 128 + cg] = v;
                    } else if (OMODE == 1) {
                        unsigned ps = pack_split(v);
                        Chi[(size_t)row * 128 + cg] = (unsigned short)ps;
                        Clo[(size_t)row * 128 + cg] = (unsigned short)(ps >> 16);
                    } else {
                        if (cg < 64) Ph[(size_t)row * 64 + cg] = rnb(v);
                        else Qf[(size_t)row * 64 + cg - 64] = v;
                    }
                }
            }
        }
    }
}

// ---------------- launch ----------------

extern "C" void kernel_launch(void* const* d_in, const int* in_sizes, int n_in,
                              void* d_out, int out_size, void* d_ws, size_t ws_size,
                              hipStream_t stream) {
    const float* x   = (const float*)d_in[0];
    const int*   ei  = (const int*)d_in[1];
    const float* Wl0 = (const float*)d_in[2];
    const float* bl0 = (const float*)d_in[3];
    const float* Wr0 = (const float*)d_in[4];
    const float* Wl1 = (const float*)d_in[5];
    const float* bl1 = (const float*)d_in[6];
    const float* Wr1 = (const float*)d_in[7];
    const float* Wl2 = (const float*)d_in[8];
    const float* bl2 = (const float*)d_in[9];
    const float* Wr2 = (const float*)d_in[10];
    const float* Wd1 = (const float*)d_in[11];
    const float* bd1 = (const float*)d_in[12];
    const float* Wd2 = (const float*)d_in[13];
    const float* bd2 = (const float*)d_in[14];
    float* out = (float*)d_out;

    char* ws = (char*)d_ws;
    size_t off = 0;
    auto alloc = [&](size_t bytes) {
        char* p = ws + off;
        off = (off + bytes + 255) & ~(size_t)255;
        return p;
    };
    int*            gcur    = (int*)alloc((size_t)NBUCK * 4);
    int*            row_ptr = (int*)alloc((size_t)NN * 4);
    int*            rc      = (int*)alloc((size_t)NN * 4);
    float*          invd    = (float*)alloc((size_t)NN * 4);
    float*          biasPQ  = (float*)alloc(128 * 4);
    unsigned short* Wh      = (unsigned short*)alloc((size_t)73728 * 2);
    unsigned short* Wl      = (unsigned short*)alloc((size_t)73728 * 2);
    int*            col     = (int*)alloc((size_t)NBUCK * CAP * 4);  // padded
    char*           R1      = alloc((size_t)NN * 128 * 4);  // 51.2 MB
    char*           R2      = alloc((size_t)NN * 128 * 4);  // 51.2 MB
    (void)ws_size;

    // R1 lifetime: [Xh 12.8 | Agg0h 12.8 | Agg0l 12.8] -> Agg1 planes (51.2) -> [Ph 12.8 | Qf 25.6]
    // R2 lifetime: tmp(CSR, 7.2MB) -> [G0h 25.6 | G0l 25.6] -> H1 in-place -> h2 planes (25.6)
    unsigned short* Xh    = (unsigned short*)R1;
    unsigned short* Agg0h = (unsigned short*)(R1 + 12800000);
    unsigned short* Agg0l = (unsigned short*)(R1 + 25600000);
    unsigned short* Agg1h = (unsigned short*)R1;
    unsigned short* Agg1l = (unsigned short*)(R1 + 25600000);
    unsigned short* Ph    = (unsigned short*)R1;
    float*          Qf    = (float*)(R1 + 12800000);
    int*            tmp   = (int*)R2;  // dead before G0's first write (L0 GEMM)
    unsigned short* G0h   = (unsigned short*)R2;
    unsigned short* G0l   = (unsigned short*)(R2 + 25600000);
    unsigned short* H1h   = G0h;
    unsigned short* H1l   = G0l;
    unsigned short* h2h   = (unsigned short*)R2;
    unsigned short* h2l   = (unsigned short*)(R2 + 12800000);

    const unsigned short* WL0h = Wh,         * WL0l = Wl;
    const unsigned short* WR0h = Wh + 8192,  * WR0l = Wl + 8192;
    const unsigned short* WL1h = Wh + 16384, * WL1l = Wl + 16384;
    const unsigned short* WR1h = Wh + 32768, * WR1l = Wl + 32768;
    const unsigned short* WPQh = Wh + 49152, * WPQl = Wl + 49152;
    const unsigned short* WD1h = Wh + 65536, * WD1l = Wl + 65536;

    const int* srce = ei;
    const int* dste = ei + NE;

    // fused conversions + gcur init (independent of CSR; must precede k_partition for gcur)
    k_conv<<<XHI_BLOCKS + 290, 256, 0, stream>>>(x, Wl0, Wr0, Wl1, Wr1, Wl2, Wr2, Wd1, bl2,
                                                 Xh, Wh, Wl, biasPQ, gcur);

    // CSR build (padded buckets: bases compile-time)
    k_partition<<<P3_BLOCKS, 256, 0, stream>>>(srce, dste, gcur, tmp);
    k_bucket<<<NBUCK, 256, 0, stream>>>(tmp, gcur, row_ptr, rc, col, invd);

    const int gGemm = (NN + 63) / 64;  // 1563
    const int gNode = NN / 4;          // 25000

    // Layer 0: 64 -> 128, ReLU.  A1 = Agg0 planes, A2 = x fp32 (on-the-fly split)
    k_agg64h<<<gNode, 256, 0, stream>>>(Xh, row_ptr, rc, col, invd, Agg0h, Agg0l);
    k_mgemm<64, 64, 0, 1, true, 1><<<gGemm, 256, 0, stream>>>(
        Agg0h, Agg0l, nullptr, nullptr, nullptr, x,
        WL0h, WL0l, WR0h, WR0l, bl0, nullptr, G0h, G0l, nullptr, nullptr,
        nullptr, nullptr, nullptr);

    // Layer 1: 128 -> 128, ReLU (in-place over G0 planes)
    k_agg128h<<<gNode, 256, 0, stream>>>(G0h, row_ptr, rc, col, invd, Agg1h, Agg1l);
    k_mgemm<128, 128, 0, 0, true, 1><<<gGemm, 256, 0, stream>>>(
        Agg1h, Agg1l, nullptr, G0h, G0l, nullptr,
        WL1h, WL1l, WR1h, WR1l, bl1, nullptr, H1h, H1l, nullptr, nullptr,
        nullptr, nullptr, nullptr);

    // Layer 2 (transform-before-aggregate): [P|Q] = h1 @ [Wl2;Wr2]^T + [0;bl2]
    k_mgemm<128, 0, 0, 0, false, 2><<<gGemm, 256, 0, stream>>>(
        H1h, H1l, nullptr, nullptr, nullptr, nullptr,
        WPQh, WPQl, nullptr, nullptr, biasPQ, nullptr, nullptr, nullptr, Ph, Qf,
        nullptr, nullptr, nullptr);
    k_aggPh<<<gNode, 256, 0, stream>>>(Ph, Qf, row_ptr, rc, col, invd, h2h, h2l);

    // Decoder: 64 -> 128 (ReLU) -> 2, final layer fused into the GEMM epilogue
    k_mgemm<64, 0, 0, 0, true, 3><<<gGemm, 256, 0, stream>>>(
        h2h, h2l, nullptr, nullptr, nullptr, nullptr,
        WD1h, WD1l, nullptr, nullptr, bd1, nullptr, nullptr, nullptr, nullptr, nullptr,
        Wd2, bd2, out);
}